// Round 11
// baseline (30.766 us; speedup 1.0000x reference)
//
#include <hip/hip_runtime.h>
#include <hip/hip_bf16.h>

typedef float    f32x4  __attribute__((ext_vector_type(4)));
typedef float    f32x16 __attribute__((ext_vector_type(16)));
typedef int      i32x4  __attribute__((ext_vector_type(4)));
typedef _Float16 f16x8  __attribute__((ext_vector_type(8)));

#define LL 256   // h*w
#define NF 32    // hidden dim
#define NCH 64   // channels

// HW pack: two f32 -> u32 of two fp16 (v_cvt_pkrtz_f16_f32)
__device__ __forceinline__ unsigned pkrtz(float lo, float hi) {
    return __builtin_bit_cast(unsigned, __builtin_amdgcn_cvt_pkrtz(lo, hi));
}

__device__ __forceinline__ f16x8 words_to_frag(unsigned w0, unsigned w1, unsigned w2, unsigned w3) {
    i32x4 w;
    w.x = (int)w0; w.y = (int)w1; w.z = (int)w2; w.w = (int)w3;
    return __builtin_bit_cast(f16x8, w);
}

// Transposed A' layout: Ap2[b][qtile][kh*2+hi][col][e]  (tile = 1024 halves = 2 KB)
// index = b*8192 + (l>>5)*1024 + ((k>>4)*2 + ((k>>3)&1))*256 + (l&31)*8 + (k&7)
__device__ __forceinline__ int a_perm(int l, int k) {
    return ((l >> 5) << 10) + ((((k >> 4) << 1) | ((k >> 3) & 1)) << 8) + ((l & 31) << 3) + (k & 7);
}

// ---------------- phase 0: A' = o@W0[:64]+b0 (fp16, transposed); B = o@W0[64:] (fp16); + tables ----
__global__ __launch_bounds__(256) void rn_pre(
    const float* __restrict__ x, const float* __restrict__ W0,
    const float* __restrict__ b0, const float* __restrict__ W1, const float* __restrict__ b1,
    const float* __restrict__ W2, const float* __restrict__ b2,
    _Float16* __restrict__ Ap, _Float16* __restrict__ Bp,
    _Float16* __restrict__ fragTab, float* __restrict__ biasTab)
{
    int tid = threadIdx.x;
    if (blockIdx.x == 0 && tid < 64) {
        const int hi2 = tid >> 5, colv = tid & 31;
        #pragma unroll
        for (int kh = 0; kh < 2; ++kh) {
            f16x8 f1, f2;
            #pragma unroll
            for (int e = 0; e < 8; ++e) {
                int k  = kh * 16 + 8 * hi2 + e;
                int bk = (k >> 2) & 3;
                int fk = (bk == 1 || bk == 2) ? (k ^ 12) : k;   // phi
                f1[e] = (_Float16)W1[k  * NF + colv];
                f2[e] = (_Float16)W2[fk * NF + colv];
            }
            *(f16x8*)(fragTab + ((0 + kh) * 64 + tid) * 8) = f1;
            *(f16x8*)(fragTab + ((2 + kh) * 64 + tid) * 8) = f2;
        }
        // biasTab[table*32 + hh*16 + r] = b{1,2}[(r&3)+8*(r>>2)+4*hh]
        int table = tid >> 5;
        int hh    = (tid >> 4) & 1;
        int r     = tid & 15;
        int row   = (r & 3) + 8 * (r >> 2) + 4 * hh;
        biasTab[table * 32 + hh * 16 + r] = table ? b2[row] : b1[row];
    }

    int gid = blockIdx.x * 256 + tid;   // 32*256*32 = 262144 threads
    int k  = gid & 31;
    int bl = gid >> 5;          // b*256 + l
    int b  = bl >> 8;
    int l  = bl & 255;
    const float* xrow = x + b * NCH * LL + l;   // x[b][ch][l]
    float accA = 0.f, accB = 0.f;
    #pragma unroll 8
    for (int ch = 0; ch < NCH; ++ch) {
        float xv = xrow[ch * LL];
        accA += xv * W0[ch * NF + k];
        accB += xv * W0[(NCH + ch) * NF + k];
    }
    Ap[b * 8192 + a_perm(l, k)] = (_Float16)(accA + b0[k]);
    Bp[gid] = (_Float16)accB;
}

// ---------------- phase 1: fused pair loop, coalesced A-tiles + 2-deep prefetch ----------------
// grid: 1024 blocks (XCD-swizzled) = 32 batches x 16 pgroups x 2 qchunks; 256 threads (4 waves).
// Wave owns 4 consecutive p's x 4 q-tiles. A' panel is pre-transposed so each fragment load is a
// fully-coalesced 1KB wave access (was a 32-line gather).
__global__ __launch_bounds__(256) void rn_main(
    const _Float16* __restrict__ Ap, const _Float16* __restrict__ Bp,
    const _Float16* __restrict__ fragTab, const float* __restrict__ biasTab,
    float* __restrict__ partials)
{
    const int tid  = threadIdx.x;
    const int lane = tid & 63;
    const int w    = tid >> 6;
    const int col  = lane & 31;
    const int hi   = lane >> 5;
    // bijective XCD-contiguous swizzle (1024 % 8 == 0)
    const int bid  = (blockIdx.x & 7) * 128 + (blockIdx.x >> 3);
    const int batch  = bid >> 5;
    const int rem    = bid & 31;
    const int pgroup = rem >> 1;    // 0..15
    const int qchunk = rem & 1;     // 0..1
    const int pbase  = pgroup * 16 + w * 4;
    const int qtile0 = qchunk * 4;  // first of 4 q-tiles

    // ---- setup from precomputed tables: coalesced vector loads ----
    f16x8 a1[2], a2[2];
    a1[0] = *(const f16x8*)(fragTab + (0 * 64 + lane) * 8);
    a1[1] = *(const f16x8*)(fragTab + (1 * 64 + lane) * 8);
    a2[0] = *(const f16x8*)(fragTab + (2 * 64 + lane) * 8);
    a2[1] = *(const f16x8*)(fragTab + (3 * 64 + lane) * 8);

    f32x16 bias1, bias2, sacc;
    {
        const f32x4* bt1 = (const f32x4*)(biasTab + hi * 16);
        const f32x4* bt2 = (const f32x4*)(biasTab + 32 + hi * 16);
        #pragma unroll
        for (int j = 0; j < 4; ++j) {
            f32x4 v1 = bt1[j], v2 = bt2[j];
            #pragma unroll
            for (int e = 0; e < 4; ++e) {
                bias1[j * 4 + e] = v1[e];
                bias2[j * 4 + e] = v2[e];
                sacc[j * 4 + e]  = 0.f;
            }
        }
    }

    // ---- B rows for the wave's 4 p's (broadcast loads, fragment order) ----
    f16x8 bq0[4], bq1[4];
    #pragma unroll
    for (int i = 0; i < 4; ++i) {
        const _Float16* Brow = Bp + (batch * LL + pbase + i) * NF + 8 * hi;
        bq0[i] = *(const f16x8*)(Brow);
        bq1[i] = *(const f16x8*)(Brow + 16);
    }

    // ---- A' tiles: transposed layout, lane offset (kh*2+hi)*256 + col*8, fully coalesced ----
    const _Float16* Atile = Ap + batch * 8192 + qtile0 * 1024;
    const int off0 = hi * 256 + col * 8;          // kh = 0
    const int off1 = 512 + hi * 256 + col * 8;    // kh = 1

    const f16x8 z8 = {};

    // 2-deep software pipeline across the 4 q-tiles
    f16x8 ca0 = *(const f16x8*)(Atile + off0);
    f16x8 ca1 = *(const f16x8*)(Atile + off1);

    #pragma unroll
    for (int t = 0; t < 4; ++t) {
        f16x8 na0, na1;
        if (t < 3) {
            na0 = *(const f16x8*)(Atile + (t + 1) * 1024 + off0);
            na1 = *(const f16x8*)(Atile + (t + 1) * 1024 + off1);
        }

        #pragma unroll
        for (int i = 0; i < 4; ++i) {
            // h1 = relu(A'[q] + B[p_i]) in fp16 -> MFMA B-operand fragments directly
            f16x8 h0 = __builtin_elementwise_max(ca0 + bq0[i], z8);
            f16x8 h1 = __builtin_elementwise_max(ca1 + bq1[i], z8);

            // layer 1 (bias as C-input)
            f32x16 acc1 = __builtin_amdgcn_mfma_f32_32x32x16_f16(a1[0], h0, bias1, 0, 0, 0);
            acc1        = __builtin_amdgcn_mfma_f32_32x32x16_f16(a1[1], h1, acc1, 0, 0, 0);

            // pack-convert (rtz) then relu as packed f16 max (commutes with rtz)
            f16x8 h2f0 = __builtin_elementwise_max(
                words_to_frag(pkrtz(acc1[0],  acc1[1]),  pkrtz(acc1[2],  acc1[3]),
                              pkrtz(acc1[4],  acc1[5]),  pkrtz(acc1[6],  acc1[7])), z8);
            f16x8 h2f1 = __builtin_elementwise_max(
                words_to_frag(pkrtz(acc1[8],  acc1[9]),  pkrtz(acc1[10], acc1[11]),
                              pkrtz(acc1[12], acc1[13]), pkrtz(acc1[14], acc1[15])), z8);

            // layer 2
            f32x16 acc2 = __builtin_amdgcn_mfma_f32_32x32x16_f16(a2[0], h2f0, bias2, 0, 0, 0);
            acc2        = __builtin_amdgcn_mfma_f32_32x32x16_f16(a2[1], h2f1, acc2, 0, 0, 0);

            // shared accumulation of relu(h3) across all chains
            sacc += __builtin_elementwise_max(acc2, (f32x16)0.0f);
        }

        ca0 = na0;
        ca1 = na1;
    }

    // ---- 3-stage LDS tail reduce ----
    __shared__ float P[256 * 20];
    __shared__ float Q[8][32];
    #pragma unroll
    for (int j = 0; j < 4; ++j) {
        f32x4 v;
        v.x = sacc[j * 4 + 0]; v.y = sacc[j * 4 + 1];
        v.z = sacc[j * 4 + 2]; v.w = sacc[j * 4 + 3];
        *(f32x4*)&P[tid * 20 + j * 4] = v;
    }
    __syncthreads();
    {
        const int row  = tid & 31;
        const int part = tid >> 5;
        const int wq   = part >> 1;
        const int colh = (part & 1) << 4;
        const int hir  = (row >> 2) & 1;
        const int rr   = (row & 3) | ((row >> 3) << 2);
        const int base = (wq * 64 + hir * 32 + colh) * 20 + rr;
        float s = 0.f;
        #pragma unroll
        for (int j = 0; j < 16; ++j) s += P[base + j * 20];
        Q[part][row] = s;
    }
    __syncthreads();
    if (tid < 32) {
        float s = 0.f;
        #pragma unroll
        for (int g = 0; g < 8; ++g) s += Q[g][tid];
        partials[bid * 32 + tid] = s;   // bid = batch*32 + rem : contiguous per batch
    }
}

// ---------------- phase 2: per-batch reduce + MLP head (32 blocks) ----------------
__global__ __launch_bounds__(256) void rn_post(
    const float* __restrict__ partials,
    const float* __restrict__ Wp, const float* __restrict__ bp,
    const float* __restrict__ Wo, const float* __restrict__ bo,
    float* __restrict__ out)
{
    const int b   = blockIdx.x;       // 32 blocks, one per batch
    const int tid = threadIdx.x;      // 256 threads
    const int grp = tid >> 5, n = tid & 31;
    __shared__ float red[8][32];
    float s = 0.f;
    #pragma unroll
    for (int j = 0; j < 4; ++j)
        s += partials[(b * 32 + grp * 4 + j) * 32 + n];
    red[grp][n] = s;
    __syncthreads();
    if (tid < 32) {
        float sv = 0.f;
        #pragma unroll
        for (int g = 0; g < 8; ++g) sv += red[g][tid];
        float f = bp[tid];
        #pragma unroll
        for (int k = 0; k < 32; ++k)
            f += __shfl(sv, k, 32) * Wp[k * 32 + tid];
        f = fmaxf(f, 0.f);
        float o = bo[tid];
        #pragma unroll
        for (int k = 0; k < 32; ++k)
            o += __shfl(f, k, 32) * Wo[k * 32 + tid];
        out[b * 32 + tid] = o;
    }
}

extern "C" void kernel_launch(void* const* d_in, const int* in_sizes, int n_in,
                              void* d_out, int out_size, void* d_ws, size_t ws_size,
                              hipStream_t stream)
{
    const float* x  = (const float*)d_in[0];
    const float* W0 = (const float*)d_in[1];
    const float* b0 = (const float*)d_in[2];
    const float* W1 = (const float*)d_in[3];
    const float* b1 = (const float*)d_in[4];
    const float* W2 = (const float*)d_in[5];
    const float* b2 = (const float*)d_in[6];
    const float* Wp = (const float*)d_in[7];
    const float* bp = (const float*)d_in[8];
    const float* Wo = (const float*)d_in[9];
    const float* bo = (const float*)d_in[10];
    float* out = (float*)d_out;

    _Float16* Ap       = (_Float16*)d_ws;                 // 262144 halves (512 KB, transposed)
    _Float16* Bp       = Ap + 32 * LL * NF;               // 262144 halves (512 KB)
    float*    partials = (float*)(Bp + 32 * LL * NF);     // 1024*32 f32 (128 KB)
    _Float16* fragTab  = (_Float16*)(partials + 2048 * 32);  // 4*64*8 halves (4 KB)
    float*    biasTab  = (float*)(fragTab + 4 * 64 * 8);     // 64 f32 (256 B)

    rn_pre <<<1024, 256, 0, stream>>>(x, W0, b0, W1, b1, W2, b2, Ap, Bp, fragTab, biasTab);
    rn_main<<<1024, 256, 0, stream>>>(Ap, Bp, fragTab, biasTab, partials);
    rn_post<<<32, 256, 0, stream>>>(partials, Wp, bp, Wo, bo, out);
}

// Round 12
// 30.030 us; speedup vs baseline: 1.0245x; 1.0245x over previous
//
#include <hip/hip_runtime.h>
#include <hip/hip_bf16.h>

typedef float    f32x4  __attribute__((ext_vector_type(4)));
typedef float    f32x16 __attribute__((ext_vector_type(16)));
typedef int      i32x4  __attribute__((ext_vector_type(4)));
typedef _Float16 f16x8  __attribute__((ext_vector_type(8)));

#define LL 256   // h*w
#define NF 32    // hidden dim
#define NCH 64   // channels

// HW pack: two f32 -> u32 of two fp16 (v_cvt_pkrtz_f16_f32)
__device__ __forceinline__ unsigned pkrtz(float lo, float hi) {
    return __builtin_bit_cast(unsigned, __builtin_amdgcn_cvt_pkrtz(lo, hi));
}

__device__ __forceinline__ f16x8 words_to_frag(unsigned w0, unsigned w1, unsigned w2, unsigned w3) {
    i32x4 w;
    w.x = (int)w0; w.y = (int)w1; w.z = (int)w2; w.w = (int)w3;
    return __builtin_bit_cast(f16x8, w);
}

// cvt f32x16 acc -> two f16x8 frags with relu after rtz (commutes)
__device__ __forceinline__ void cvt_relu(const f32x16& a, f16x8& f0, f16x8& f1) {
    const f16x8 z8 = {};
    f0 = __builtin_elementwise_max(
        words_to_frag(pkrtz(a[0],  a[1]),  pkrtz(a[2],  a[3]),
                      pkrtz(a[4],  a[5]),  pkrtz(a[6],  a[7])), z8);
    f1 = __builtin_elementwise_max(
        words_to_frag(pkrtz(a[8],  a[9]),  pkrtz(a[10], a[11]),
                      pkrtz(a[12], a[13]), pkrtz(a[14], a[15])), z8);
}

// Transposed A' layout: Ap2[b][qtile][kh*2+hi][col][e]  (tile = 1024 halves = 2 KB)
__device__ __forceinline__ int a_perm(int l, int k) {
    return ((l >> 5) << 10) + ((((k >> 4) << 1) | ((k >> 3) & 1)) << 8) + ((l & 31) << 3) + (k & 7);
}

// ---------------- phase 0: A' = o@W0[:64]+b0 (fp16, transposed); B = o@W0[64:] (fp16); + tables ----
__global__ __launch_bounds__(256) void rn_pre(
    const float* __restrict__ x, const float* __restrict__ W0,
    const float* __restrict__ b0, const float* __restrict__ W1, const float* __restrict__ b1,
    const float* __restrict__ W2, const float* __restrict__ b2,
    _Float16* __restrict__ Ap, _Float16* __restrict__ Bp,
    _Float16* __restrict__ fragTab, float* __restrict__ biasTab)
{
    int tid = threadIdx.x;
    if (blockIdx.x == 0 && tid < 64) {
        const int hi2 = tid >> 5, colv = tid & 31;
        #pragma unroll
        for (int kh = 0; kh < 2; ++kh) {
            f16x8 f1, f2;
            #pragma unroll
            for (int e = 0; e < 8; ++e) {
                int k  = kh * 16 + 8 * hi2 + e;
                int bk = (k >> 2) & 3;
                int fk = (bk == 1 || bk == 2) ? (k ^ 12) : k;   // phi
                f1[e] = (_Float16)W1[k  * NF + colv];
                f2[e] = (_Float16)W2[fk * NF + colv];
            }
            *(f16x8*)(fragTab + ((0 + kh) * 64 + tid) * 8) = f1;
            *(f16x8*)(fragTab + ((2 + kh) * 64 + tid) * 8) = f2;
        }
        int table = tid >> 5;
        int hh    = (tid >> 4) & 1;
        int r     = tid & 15;
        int row   = (r & 3) + 8 * (r >> 2) + 4 * hh;
        biasTab[table * 32 + hh * 16 + r] = table ? b2[row] : b1[row];
    }

    int gid = blockIdx.x * 256 + tid;   // 32*256*32 = 262144 threads
    int k  = gid & 31;
    int bl = gid >> 5;          // b*256 + l
    int b  = bl >> 8;
    int l  = bl & 255;
    const float* xrow = x + b * NCH * LL + l;   // x[b][ch][l]
    float accA = 0.f, accB = 0.f;
    #pragma unroll 8
    for (int ch = 0; ch < NCH; ++ch) {
        float xv = xrow[ch * LL];
        accA += xv * W0[ch * NF + k];
        accB += xv * W0[(NCH + ch) * NF + k];
    }
    Ap[b * 8192 + a_perm(l, k)] = (_Float16)(accA + b0[k]);
    Bp[gid] = (_Float16)accB;
}

// ---------------- phase 1: fused pair loop, STAGED 2-chain ILP ----------------
// grid: 1024 blocks (XCD-swizzled) = 32 batches x 16 pgroups x 2 qchunks; 256 threads (4 waves).
// Wave owns 4 consecutive p's x 4 q-tiles. Chains staged in PAIRS with named registers so the
// compiler keeps both in flight: hbuild(a,b) -> 4x MFMA1 -> cvt(a,b) -> 4x MFMA2 -> accum(a,b).
// Separate sacc0/sacc1 accumulators break the cross-chain serial add dependency.
__global__ __launch_bounds__(256) void rn_main(
    const _Float16* __restrict__ Ap, const _Float16* __restrict__ Bp,
    const _Float16* __restrict__ fragTab, const float* __restrict__ biasTab,
    float* __restrict__ partials)
{
    const int tid  = threadIdx.x;
    const int lane = tid & 63;
    const int w    = tid >> 6;
    const int col  = lane & 31;
    const int hi   = lane >> 5;
    const int bid  = (blockIdx.x & 7) * 128 + (blockIdx.x >> 3);
    const int batch  = bid >> 5;
    const int rem    = bid & 31;
    const int pgroup = rem >> 1;    // 0..15
    const int qchunk = rem & 1;     // 0..1
    const int pbase  = pgroup * 16 + w * 4;
    const int qtile0 = qchunk * 4;  // first of 4 q-tiles

    // ---- setup from precomputed tables ----
    f16x8 a1[2], a2[2];
    a1[0] = *(const f16x8*)(fragTab + (0 * 64 + lane) * 8);
    a1[1] = *(const f16x8*)(fragTab + (1 * 64 + lane) * 8);
    a2[0] = *(const f16x8*)(fragTab + (2 * 64 + lane) * 8);
    a2[1] = *(const f16x8*)(fragTab + (3 * 64 + lane) * 8);

    f32x16 bias1, bias2, sacc0, sacc1;
    {
        const f32x4* bt1 = (const f32x4*)(biasTab + hi * 16);
        const f32x4* bt2 = (const f32x4*)(biasTab + 32 + hi * 16);
        #pragma unroll
        for (int j = 0; j < 4; ++j) {
            f32x4 v1 = bt1[j], v2 = bt2[j];
            #pragma unroll
            for (int e = 0; e < 4; ++e) {
                bias1[j * 4 + e] = v1[e];
                bias2[j * 4 + e] = v2[e];
                sacc0[j * 4 + e] = 0.f;
                sacc1[j * 4 + e] = 0.f;
            }
        }
    }

    // ---- B rows for the wave's 4 p's ----
    f16x8 bq0[4], bq1[4];
    #pragma unroll
    for (int i = 0; i < 4; ++i) {
        const _Float16* Brow = Bp + (batch * LL + pbase + i) * NF + 8 * hi;
        bq0[i] = *(const f16x8*)(Brow);
        bq1[i] = *(const f16x8*)(Brow + 16);
    }

    // ---- A' tiles: transposed layout, fully coalesced ----
    const _Float16* Atile = Ap + batch * 8192 + qtile0 * 1024;
    const int off0 = hi * 256 + col * 8;          // kh = 0
    const int off1 = 512 + hi * 256 + col * 8;    // kh = 1

    const f16x8 z8 = {};

    f16x8 ca0 = *(const f16x8*)(Atile + off0);
    f16x8 ca1 = *(const f16x8*)(Atile + off1);

    #pragma unroll
    for (int t = 0; t < 4; ++t) {
        f16x8 na0, na1;
        if (t < 3) {
            na0 = *(const f16x8*)(Atile + (t + 1) * 1024 + off0);
            na1 = *(const f16x8*)(Atile + (t + 1) * 1024 + off1);
        }

        #pragma unroll
        for (int ig = 0; ig < 2; ++ig) {
            const int i0 = ig * 2, i1 = ig * 2 + 1;

            // --- stage 1: both chains' h1 fragments ---
            f16x8 h0a = __builtin_elementwise_max(ca0 + bq0[i0], z8);
            f16x8 h1a = __builtin_elementwise_max(ca1 + bq1[i0], z8);
            f16x8 h0b = __builtin_elementwise_max(ca0 + bq0[i1], z8);
            f16x8 h1b = __builtin_elementwise_max(ca1 + bq1[i1], z8);

            // --- stage 2: 4x layer-1 MFMA back-to-back ---
            f32x16 acc1a = __builtin_amdgcn_mfma_f32_32x32x16_f16(a1[0], h0a, bias1, 0, 0, 0);
            f32x16 acc1b = __builtin_amdgcn_mfma_f32_32x32x16_f16(a1[0], h0b, bias1, 0, 0, 0);
            acc1a = __builtin_amdgcn_mfma_f32_32x32x16_f16(a1[1], h1a, acc1a, 0, 0, 0);
            acc1b = __builtin_amdgcn_mfma_f32_32x32x16_f16(a1[1], h1b, acc1b, 0, 0, 0);

            // --- stage 3: both cvt epilogues ---
            f16x8 h2f0a, h2f1a, h2f0b, h2f1b;
            cvt_relu(acc1a, h2f0a, h2f1a);
            cvt_relu(acc1b, h2f0b, h2f1b);

            // --- stage 4: 4x layer-2 MFMA back-to-back ---
            f32x16 acc2a = __builtin_amdgcn_mfma_f32_32x32x16_f16(a2[0], h2f0a, bias2, 0, 0, 0);
            f32x16 acc2b = __builtin_amdgcn_mfma_f32_32x32x16_f16(a2[0], h2f0b, bias2, 0, 0, 0);
            acc2a = __builtin_amdgcn_mfma_f32_32x32x16_f16(a2[1], h2f1a, acc2a, 0, 0, 0);
            acc2b = __builtin_amdgcn_mfma_f32_32x32x16_f16(a2[1], h2f1b, acc2b, 0, 0, 0);

            // --- stage 5: independent accumulators ---
            sacc0 += __builtin_elementwise_max(acc2a, (f32x16)0.0f);
            sacc1 += __builtin_elementwise_max(acc2b, (f32x16)0.0f);
        }

        ca0 = na0;
        ca1 = na1;
    }

    f32x16 sacc = sacc0 + sacc1;

    // ---- 3-stage LDS tail reduce ----
    __shared__ float P[256 * 20];
    __shared__ float Q[8][32];
    #pragma unroll
    for (int j = 0; j < 4; ++j) {
        f32x4 v;
        v.x = sacc[j * 4 + 0]; v.y = sacc[j * 4 + 1];
        v.z = sacc[j * 4 + 2]; v.w = sacc[j * 4 + 3];
        *(f32x4*)&P[tid * 20 + j * 4] = v;
    }
    __syncthreads();
    {
        const int row  = tid & 31;
        const int part = tid >> 5;
        const int wq   = part >> 1;
        const int colh = (part & 1) << 4;
        const int hir  = (row >> 2) & 1;
        const int rr   = (row & 3) | ((row >> 3) << 2);
        const int base = (wq * 64 + hir * 32 + colh) * 20 + rr;
        float s = 0.f;
        #pragma unroll
        for (int j = 0; j < 16; ++j) s += P[base + j * 20];
        Q[part][row] = s;
    }
    __syncthreads();
    if (tid < 32) {
        float s = 0.f;
        #pragma unroll
        for (int g = 0; g < 8; ++g) s += Q[g][tid];
        partials[bid * 32 + tid] = s;
    }
}

// ---------------- phase 2: per-batch reduce + MLP head (32 blocks) ----------------
__global__ __launch_bounds__(256) void rn_post(
    const float* __restrict__ partials,
    const float* __restrict__ Wp, const float* __restrict__ bp,
    const float* __restrict__ Wo, const float* __restrict__ bo,
    float* __restrict__ out)
{
    const int b   = blockIdx.x;
    const int tid = threadIdx.x;
    const int grp = tid >> 5, n = tid & 31;
    __shared__ float red[8][32];
    float s = 0.f;
    #pragma unroll
    for (int j = 0; j < 4; ++j)
        s += partials[(b * 32 + grp * 4 + j) * 32 + n];
    red[grp][n] = s;
    __syncthreads();
    if (tid < 32) {
        float sv = 0.f;
        #pragma unroll
        for (int g = 0; g < 8; ++g) sv += red[g][tid];
        float f = bp[tid];
        #pragma unroll
        for (int k = 0; k < 32; ++k)
            f += __shfl(sv, k, 32) * Wp[k * 32 + tid];
        f = fmaxf(f, 0.f);
        float o = bo[tid];
        #pragma unroll
        for (int k = 0; k < 32; ++k)
            o += __shfl(f, k, 32) * Wo[k * 32 + tid];
        out[b * 32 + tid] = o;
    }
}

extern "C" void kernel_launch(void* const* d_in, const int* in_sizes, int n_in,
                              void* d_out, int out_size, void* d_ws, size_t ws_size,
                              hipStream_t stream)
{
    const float* x  = (const float*)d_in[0];
    const float* W0 = (const float*)d_in[1];
    const float* b0 = (const float*)d_in[2];
    const float* W1 = (const float*)d_in[3];
    const float* b1 = (const float*)d_in[4];
    const float* W2 = (const float*)d_in[5];
    const float* b2 = (const float*)d_in[6];
    const float* Wp = (const float*)d_in[7];
    const float* bp = (const float*)d_in[8];
    const float* Wo = (const float*)d_in[9];
    const float* bo = (const float*)d_in[10];
    float* out = (float*)d_out;

    _Float16* Ap       = (_Float16*)d_ws;                 // 262144 halves (512 KB, transposed)
    _Float16* Bp       = Ap + 32 * LL * NF;               // 262144 halves (512 KB)
    float*    partials = (float*)(Bp + 32 * LL * NF);     // 1024*32 f32 (128 KB)
    _Float16* fragTab  = (_Float16*)(partials + 2048 * 32);  // 4*64*8 halves (4 KB)
    float*    biasTab  = (float*)(fragTab + 4 * 64 * 8);     // 64 f32 (256 B)

    rn_pre <<<1024, 256, 0, stream>>>(x, W0, b0, W1, b1, W2, b2, Ap, Bp, fragTab, biasTab);
    rn_main<<<1024, 256, 0, stream>>>(Ap, Bp, fragTab, biasTab, partials);
    rn_post<<<32, 256, 0, stream>>>(partials, Wp, bp, Wo, bo, out);
}